// Round 2
// baseline (295.183 us; speedup 1.0000x reference)
//
#include <hip/hip_runtime.h>

#define NB 8
#define NL 2048
#define ND 128
#define NH 128
#define MASKVAL (-1e30f)

typedef __attribute__((ext_vector_type(8))) short short8;
typedef __attribute__((ext_vector_type(4))) short short4v;
typedef __attribute__((ext_vector_type(4))) float f32x4;

__device__ __forceinline__ unsigned short bf16_rn(float f) {
  unsigned u = __float_as_uint(f);
  u += 0x7fffu + ((u >> 16) & 1u);
  return (unsigned short)(u >> 16);
}
__device__ __forceinline__ float bf16_tof(unsigned short h) {
  return __uint_as_float(((unsigned)h) << 16);
}

// ---------------- Kernel 0: transpose + hi/lo split the weight matrices ----
// Wt[h][d] = pack( lo16 = bf16(W[d][h]), hi16 = bf16(residual) )
__global__ __launch_bounds__(256) void wprep_kernel(
    const float* __restrict__ Wq, const float* __restrict__ Wk,
    unsigned* __restrict__ Wqt, unsigned* __restrict__ Wkt)
{
  const float* W = blockIdx.x ? Wk : Wq;
  unsigned* Wt = blockIdx.x ? Wkt : Wqt;
  for (int i = threadIdx.x; i < ND * NH; i += 256) {
    int h = i >> 7, d = i & 127;
    float v = W[d * NH + h];
    unsigned short hb = bf16_rn(v);
    unsigned short lb = bf16_rn(v - bf16_tof(hb));
    Wt[i] = ((unsigned)lb << 16) | (unsigned)hb;
  }
}

// ---------------- Kernel 1: projection  q = X @ W  (split-bf16 MFMA) -------
// grid (M/64, 2); block 256 (4 waves, 16 rows each). Writes packed hi|lo u32.
__global__ __launch_bounds__(256) void proj_kernel(
    const float* __restrict__ query, const float* __restrict__ key,
    const unsigned* __restrict__ Wqt, const unsigned* __restrict__ Wkt,
    unsigned* __restrict__ qhl, unsigned* __restrict__ khl)
{
  const float* X = blockIdx.y ? key : query;
  const unsigned* Wt = blockIdx.y ? Wkt : Wqt;
  unsigned* outp = blockIdx.y ? khl : qhl;

  int tid = threadIdx.x;
  int wave = tid >> 6, lane = tid & 63;
  int lr = lane & 15, dg = lane >> 4;
  int arow = blockIdx.x * 64 + wave * 16 + lr;

  // A fragments: rows of X, split hi/lo
  short8 ah[4], al[4];
  const float* xr = X + (size_t)arow * ND;
#pragma unroll
  for (int ks = 0; ks < 4; ++ks) {
    float4 v0 = *(const float4*)(xr + ks * 32 + dg * 8);
    float4 v1 = *(const float4*)(xr + ks * 32 + dg * 8 + 4);
    float vv[8] = {v0.x, v0.y, v0.z, v0.w, v1.x, v1.y, v1.z, v1.w};
    short8 h, l;
#pragma unroll
    for (int j = 0; j < 8; ++j) {
      unsigned short hb = bf16_rn(vv[j]);
      h[j] = (short)hb;
      l[j] = (short)bf16_rn(vv[j] - bf16_tof(hb));
    }
    ah[ks] = h; al[ks] = l;
  }

#pragma unroll
  for (int cf = 0; cf < 8; ++cf) {
    f32x4 acc = {0.f, 0.f, 0.f, 0.f};
    int col = cf * 16 + lr;
    const unsigned* wp = Wt + (size_t)col * ND;
#pragma unroll
    for (int ks = 0; ks < 4; ++ks) {
      uint4 w0 = *(const uint4*)(wp + ks * 32 + dg * 8);
      uint4 w1 = *(const uint4*)(wp + ks * 32 + dg * 8 + 4);
      unsigned wv[8] = {w0.x, w0.y, w0.z, w0.w, w1.x, w1.y, w1.z, w1.w};
      short8 wh, wl;
#pragma unroll
      for (int j = 0; j < 8; ++j) {
        wh[j] = (short)(wv[j] & 0xffffu);
        wl[j] = (short)(wv[j] >> 16);
      }
      acc = __builtin_amdgcn_mfma_f32_16x16x32_bf16(ah[ks], wh, acc, 0, 0, 0);
      acc = __builtin_amdgcn_mfma_f32_16x16x32_bf16(al[ks], wh, acc, 0, 0, 0);
      acc = __builtin_amdgcn_mfma_f32_16x16x32_bf16(ah[ks], wl, acc, 0, 0, 0);
    }
#pragma unroll
    for (int r = 0; r < 4; ++r) {
      int orow = blockIdx.x * 64 + wave * 16 + dg * 4 + r;
      float v = acc[r];
      unsigned short hb = bf16_rn(v);
      unsigned short lb = bf16_rn(v - bf16_tof(hb));
      outp[(size_t)orow * NH + col] = ((unsigned)lb << 16) | (unsigned)hb;
    }
  }
}

// ---------------- Kernel 2: fused flash attention --------------------------
// grid B*L/32 blocks; 4 waves. Waves {0,1}: rows {0-15,16-31} x even K-tiles;
// waves {2,3}: same rows x odd K-tiles. 32-key tiles, split-bf16 QK^T,
// online softmax, bf16 PV, pair merge at end.
__global__ __launch_bounds__(256) void attn_kernel(
    const unsigned* __restrict__ qhl, const unsigned* __restrict__ khl,
    const float* __restrict__ value, const float* __restrict__ mask,
    float* __restrict__ out)
{
  __shared__ short Kh[2][32][136];
  __shared__ short Kl[2][32][136];
  __shared__ short Vt[2][128][40];
  __shared__ short Plds[4][16][40];
  __shared__ float Msk[2][32];

  int tid = threadIdx.x;
  int wave = tid >> 6, lane = tid & 63;
  int lr = lane & 15, dg = lane >> 4;
  int b = blockIdx.x >> 6, qt = blockIdx.x & 63;
  int wr = wave & 1, wk = wave >> 1;
  int q0 = qt * 32;

  // Q fragments for this wave's 16 rows (packed hi|lo)
  short8 qh[4], ql[4];
  {
    const unsigned* qp = qhl + (size_t)(b * NL + q0 + wr * 16 + lr) * NH;
#pragma unroll
    for (int ks = 0; ks < 4; ++ks) {
      uint4 u0 = *(const uint4*)(qp + ks * 32 + dg * 8);
      uint4 u1 = *(const uint4*)(qp + ks * 32 + dg * 8 + 4);
      unsigned uv[8] = {u0.x, u0.y, u0.z, u0.w, u1.x, u1.y, u1.z, u1.w};
      short8 h, l;
#pragma unroll
      for (int j = 0; j < 8; ++j) {
        h[j] = (short)(uv[j] & 0xffffu);
        l[j] = (short)(uv[j] >> 16);
      }
      qh[ks] = h; ql[ks] = l;
    }
  }

  f32x4 accv[8];
#pragma unroll
  for (int f = 0; f < 8; ++f) accv[f] = (f32x4){0.f, 0.f, 0.f, 0.f};
  float mrow[4] = {-__builtin_inff(), -__builtin_inff(), -__builtin_inff(), -__builtin_inff()};
  float lrow[4] = {0.f, 0.f, 0.f, 0.f};

  for (int it = 0; it < NL / 32; it += 2) {
    // ---- stage two K/V tiles (threads 0-127 -> slot 0, 128-255 -> slot 1)
    {
      int s = tid >> 7;
      int t = tid & 127;
      int kt = it + s;
      int kbase = b * NL + kt * 32;
#pragma unroll
      for (int c = 0; c < 8; ++c) {
        int id = c * 128 + t;         // 0..1023 : 32 keys x 32 uint4-chunks
        int keyl = id >> 5;
        int dch = id & 31;
        uint4 u = *(const uint4*)(khl + (size_t)(kbase + keyl) * NH + dch * 4);
        short4v hv = {(short)(u.x & 0xffffu), (short)(u.y & 0xffffu),
                      (short)(u.z & 0xffffu), (short)(u.w & 0xffffu)};
        short4v lv = {(short)(u.x >> 16), (short)(u.y >> 16),
                      (short)(u.z >> 16), (short)(u.w >> 16)};
        *(short4v*)&Kh[s][keyl][dch * 4] = hv;
        *(short4v*)&Kl[s][keyl][dch * 4] = lv;
        float4 fv = *(const float4*)(value + (size_t)(kbase + keyl) * ND + dch * 4);
        Vt[s][dch * 4 + 0][keyl] = (short)bf16_rn(fv.x);
        Vt[s][dch * 4 + 1][keyl] = (short)bf16_rn(fv.y);
        Vt[s][dch * 4 + 2][keyl] = (short)bf16_rn(fv.z);
        Vt[s][dch * 4 + 3][keyl] = (short)bf16_rn(fv.w);
      }
      if (t < 32) Msk[s][t] = mask[kbase + t];
    }
    __syncthreads();

    // ---- compute this wave's tile (slot = wk)
    {
      const int s = wk;
      f32x4 sc0 = {0.f, 0.f, 0.f, 0.f}, sc1 = {0.f, 0.f, 0.f, 0.f};
#pragma unroll
      for (int ks = 0; ks < 4; ++ks) {
        short8 b0h = *(const short8*)&Kh[s][lr][ks * 32 + dg * 8];
        short8 b0l = *(const short8*)&Kl[s][lr][ks * 32 + dg * 8];
        short8 b1h = *(const short8*)&Kh[s][16 + lr][ks * 32 + dg * 8];
        short8 b1l = *(const short8*)&Kl[s][16 + lr][ks * 32 + dg * 8];
        sc0 = __builtin_amdgcn_mfma_f32_16x16x32_bf16(qh[ks], b0h, sc0, 0, 0, 0);
        sc1 = __builtin_amdgcn_mfma_f32_16x16x32_bf16(qh[ks], b1h, sc1, 0, 0, 0);
        sc0 = __builtin_amdgcn_mfma_f32_16x16x32_bf16(ql[ks], b0h, sc0, 0, 0, 0);
        sc1 = __builtin_amdgcn_mfma_f32_16x16x32_bf16(ql[ks], b1h, sc1, 0, 0, 0);
        sc0 = __builtin_amdgcn_mfma_f32_16x16x32_bf16(qh[ks], b0l, sc0, 0, 0, 0);
        sc1 = __builtin_amdgcn_mfma_f32_16x16x32_bf16(qh[ks], b1l, sc1, 0, 0, 0);
      }
      float mk0 = Msk[s][lr], mk1 = Msk[s][16 + lr];
      float pr0[4], pr1[4];
#pragma unroll
      for (int r = 0; r < 4; ++r) {
        float s0 = mk0 * sc0[r] + (1.f - mk0) * MASKVAL;
        float s1 = mk1 * sc1[r] + (1.f - mk1) * MASKVAL;
        float vmax = fmaxf(s0, s1);
        vmax = fmaxf(vmax, __shfl_xor(vmax, 1));
        vmax = fmaxf(vmax, __shfl_xor(vmax, 2));
        vmax = fmaxf(vmax, __shfl_xor(vmax, 4));
        vmax = fmaxf(vmax, __shfl_xor(vmax, 8));
        float mn = fmaxf(mrow[r], vmax);
        float alpha = __expf(mrow[r] - mn);
        float p0 = __expf(s0 - mn);
        float p1 = __expf(s1 - mn);
        float ps = p0 + p1;
        ps += __shfl_xor(ps, 1);
        ps += __shfl_xor(ps, 2);
        ps += __shfl_xor(ps, 4);
        ps += __shfl_xor(ps, 8);
        mrow[r] = mn;
        lrow[r] = lrow[r] * alpha + ps;
        pr0[r] = p0; pr1[r] = p1;
#pragma unroll
        for (int f = 0; f < 8; ++f) accv[f][r] *= alpha;
      }
      // P -> LDS (per-wave private) for A-fragment transpose
#pragma unroll
      for (int r = 0; r < 4; ++r) {
        Plds[wave][dg * 4 + r][lr] = (short)bf16_rn(pr0[r]);
        Plds[wave][dg * 4 + r][16 + lr] = (short)bf16_rn(pr1[r]);
      }
      short8 pa = *(const short8*)&Plds[wave][lr][dg * 8];
#pragma unroll
      for (int f = 0; f < 8; ++f) {
        short8 bv = *(const short8*)&Vt[s][f * 16 + lr][dg * 8];
        accv[f] = __builtin_amdgcn_mfma_f32_16x16x32_bf16(pa, bv, accv[f], 0, 0, 0);
      }
    }
    __syncthreads();
  }

  // ---- merge wave pairs (0<-2 rows 0-15, 1<-3 rows 16-31), write out -----
  float* obuf = (float*)&Kh[0][0][0];    // 2*16*128 f32 = 16 KB, fits in Kh
  float* mlbuf = (float*)&Plds[0][0][0]; // 2*16*2 f32
  if (wk == 1) {
#pragma unroll
    for (int f = 0; f < 8; ++f)
#pragma unroll
      for (int r = 0; r < 4; ++r)
        obuf[(wr * 16 + dg * 4 + r) * 128 + f * 16 + lr] = accv[f][r];
    if (lr == 0) {
#pragma unroll
      for (int r = 0; r < 4; ++r) {
        mlbuf[(wr * 16 + dg * 4 + r) * 2 + 0] = mrow[r];
        mlbuf[(wr * 16 + dg * 4 + r) * 2 + 1] = lrow[r];
      }
    }
  }
  __syncthreads();
  if (wk == 0) {
#pragma unroll
    for (int r = 0; r < 4; ++r) {
      int rowl = wr * 16 + dg * 4 + r;
      float m2 = mlbuf[rowl * 2 + 0], l2 = mlbuf[rowl * 2 + 1];
      float mm = fmaxf(mrow[r], m2);
      float a1 = __expf(mrow[r] - mm), a2 = __expf(m2 - mm);
      float linv = 1.f / (a1 * lrow[r] + a2 * l2);
      int grow = b * NL + q0 + rowl;
#pragma unroll
      for (int f = 0; f < 8; ++f) {
        float o = (a1 * accv[f][r] + a2 * obuf[rowl * 128 + f * 16 + lr]) * linv;
        out[(size_t)grow * ND + f * 16 + lr] = o;
      }
    }
  }
}

extern "C" void kernel_launch(void* const* d_in, const int* in_sizes, int n_in,
                              void* d_out, int out_size, void* d_ws, size_t ws_size,
                              hipStream_t stream) {
  (void)in_sizes; (void)n_in; (void)out_size; (void)ws_size;
  const float* query = (const float*)d_in[0];
  const float* key   = (const float*)d_in[1];
  const float* value = (const float*)d_in[2];
  const float* mask  = (const float*)d_in[3];
  const float* Wq    = (const float*)d_in[4];
  const float* Wk    = (const float*)d_in[5];
  float* out = (float*)d_out;

  unsigned* Wqt = (unsigned*)d_ws;
  unsigned* Wkt = Wqt + ND * NH;
  unsigned* qhl = Wkt + ND * NH;
  unsigned* khl = qhl + (size_t)NB * NL * NH;

  wprep_kernel<<<dim3(2), dim3(256), 0, stream>>>(Wq, Wk, Wqt, Wkt);
  proj_kernel<<<dim3(NB * NL / 64, 2), dim3(256), 0, stream>>>(query, key, Wqt, Wkt, qhl, khl);
  attn_kernel<<<dim3(NB * NL / 32), dim3(256), 0, stream>>>(qhl, khl, value, mask, out);
}